// Round 4
// baseline (1075.906 us; speedup 1.0000x reference)
//
#include <hip/hip_runtime.h>
#include <hip/hip_bf16.h>
#include <stdint.h>
#include <stddef.h>

// SAE forward, fp32 in / fp32 out:
//   x_rec = topk32(relu((x - b_dec) @ W_enc^T + b_enc)) @ W_dec + b_dec
// B=4096, D=1024, H=32768, k=32.
//
// R4: R3 core-dumped because its FIXED 73MB ws header (full bf16 W copy)
// overran ws_size (evidence: R1/R2 with ~17MB footprints ran; R3 crashed).
// Now W is converted to bf16 PER CHUNK (Hc cols at a time), so the whole
// footprint adapts to ws_size:
//   [0,8MB)      xbf bf16[4096][1024]
//   [8MB,8.75MB) cand u32[4096][48]
//   [9MB, +Hc*2KB)        Wbc bf16[Hc][1024]     (current chunk of W_enc)
//   [9MB+Hc*2KB, ...)     scores bf16[4096][Hc]
// min footprint (Hc=128) ~= 10.3 MB.
// Selection on bf16 scores -> top-48 candidates; exact fp64 rescore of the
// 48 from the original fp32 inputs -> top-32 (numpy tie semantics) -> decode.

#define BROWS 4096
#define DIN   1024
#define HID   32768
#define KTOP  32
#define KC    48   // candidate count
#define PT    16   // per-thread register list length in topk

typedef short short8_t __attribute__((ext_vector_type(8)));
typedef float fx4 __attribute__((ext_vector_type(4)));

__device__ __forceinline__ unsigned short f2bf(float f) {
  unsigned u = __float_as_uint(f);
  u += 0x7FFFu + ((u >> 16) & 1u);   // RNE (no NaNs/infs in this data)
  return (unsigned short)(u >> 16);
}

// ---------------- convert one chunk of W_enc (rows [c0,c0+Hc)) fp32 -> bf16 ----------------
__global__ __launch_bounds__(256) void conv_wc(const float* __restrict__ W,
                                               unsigned short* __restrict__ Wbc, int c0) {
  int base = (blockIdx.x * 256 + threadIdx.x) * 4;  // chunk-local element
  float4 v = *(const float4*)(W + (size_t)c0 * DIN + base);
  ushort4 o;
  o.x = f2bf(v.x); o.y = f2bf(v.y); o.z = f2bf(v.z); o.w = f2bf(v.w);
  *(ushort4*)(Wbc + base) = o;
}

// ---------------- xbf = bf16(x - b_dec) ----------------
__global__ __launch_bounds__(256) void prep_x(const float* __restrict__ x,
                                              const float* __restrict__ bdec,
                                              unsigned short* __restrict__ xbf) {
  int base = (blockIdx.x * 256 + threadIdx.x) * 4;
  int col = base & (DIN - 1);
  float4 xv = *(const float4*)(x + base);
  float4 bv = *(const float4*)(bdec + col);
  ushort4 o;
  o.x = f2bf(xv.x - bv.x); o.y = f2bf(xv.y - bv.y);
  o.z = f2bf(xv.z - bv.z); o.w = f2bf(xv.w - bv.w);
  *(ushort4*)(xbf + base) = o;
}

// ---------------- init candidate keys ----------------
__global__ __launch_bounds__(256) void init_cand(unsigned* __restrict__ cand) {
  int i = blockIdx.x * 256 + threadIdx.x;
  if (i < BROWS * KC) cand[i] = 0u;
}

// ---------------- GEMM: approx scores (bf16) = relu(xbf @ Wbc^T + b_enc) ----------------
// 128x128 tile, 4 waves x (4x4 of 16x16x32 bf16 MFMA), BK=64, XOR-swizzled LDS
// (verified m92/m97 structure).
#define BM 128
#define BN 128
#define BK 64

__global__ __launch_bounds__(256) void gemm_scores(
    const unsigned short* __restrict__ A,     // xbf [BROWS][DIN]
    const unsigned short* __restrict__ W,     // Wbc [Hc][DIN] (chunk-local)
    const float* __restrict__ benc,           // [HID] fp32 (global)
    unsigned short* __restrict__ scores,      // [BROWS][Hc] bf16 (chunk-local)
    int Hc, int c0) {
  __shared__ unsigned short As[BM * BK];
  __shared__ unsigned short Bs[BN * BK];

  const int t    = threadIdx.x;
  const int lane = t & 63;
  const int wv   = t >> 6;
  const int wm   = wv & 1;
  const int wn   = wv >> 1;
  const int l16  = lane & 15;
  const int quad = lane >> 4;

  const int row0  = blockIdx.y * BM;
  const int colc0 = blockIdx.x * BN;  // chunk-local

  fx4 zero = {0.f, 0.f, 0.f, 0.f};
  fx4 acc[4][4];
#pragma unroll
  for (int i = 0; i < 4; ++i)
#pragma unroll
    for (int j = 0; j < 4; ++j) acc[i][j] = zero;

  const unsigned short* Abase = A + (size_t)row0 * DIN;
  const unsigned short* Wbase = W + (size_t)colc0 * DIN;

  int srow[4], spos[4], sk8[4];
#pragma unroll
  for (int r = 0; r < 4; ++r) {
    int c = r * 256 + t;
    srow[r] = c >> 3;
    sk8[r]  = c & 7;
    spos[r] = (c & 7) ^ (srow[r] & 7);
  }

  for (int k0 = 0; k0 < DIN; k0 += BK) {
    short8_t av[4], wvv[4];
#pragma unroll
    for (int r = 0; r < 4; ++r) {
      int gofs = srow[r] * DIN + k0 + sk8[r] * 8;
      av[r]  = *(const short8_t*)(Abase + gofs);
      wvv[r] = *(const short8_t*)(Wbase + gofs);
    }
#pragma unroll
    for (int r = 0; r < 4; ++r) {
      int lofs = srow[r] * BK + spos[r] * 8;
      *(short8_t*)(As + lofs) = av[r];
      *(short8_t*)(Bs + lofs) = wvv[r];
    }
    __syncthreads();
#pragma unroll
    for (int s = 0; s < BK / 32; ++s) {
      short8_t af[4], bfr[4];
      int pos = (((s * 4) + quad) ^ (l16 & 7)) * 8;
#pragma unroll
      for (int mt = 0; mt < 4; ++mt)
        af[mt] = *(const short8_t*)(As + (wm * 64 + mt * 16 + l16) * BK + pos);
#pragma unroll
      for (int nt = 0; nt < 4; ++nt)
        bfr[nt] = *(const short8_t*)(Bs + (wn * 64 + nt * 16 + l16) * BK + pos);
#pragma unroll
      for (int mt = 0; mt < 4; ++mt)
#pragma unroll
        for (int nt = 0; nt < 4; ++nt)
          acc[mt][nt] = __builtin_amdgcn_mfma_f32_16x16x32_bf16(af[mt], bfr[nt], acc[mt][nt], 0, 0, 0);
    }
    __syncthreads();
  }

  // epilogue: +bias, relu, bf16 store. C/D map: col=lane&15, row=quad*4+reg.
#pragma unroll
  for (int nt = 0; nt < 4; ++nt) {
    int colc = colc0 + wn * 64 + nt * 16 + l16;    // chunk-local col
    float bv = benc[c0 + colc];
#pragma unroll
    for (int mt = 0; mt < 4; ++mt) {
      int rbase = row0 + wm * 64 + mt * 16 + quad * 4;
#pragma unroll
      for (int rg = 0; rg < 4; ++rg) {
        float v = acc[mt][nt][rg] + bv;
        scores[(size_t)(rbase + rg) * Hc + colc] = f2bf(v > 0.f ? v : 0.f);
      }
    }
  }
}

// ---------------- top-48 candidates per row ----------------
// key = bf16bits<<16 | (0x7FFF - global_col): monotone for relu'd (>=0) bf16,
// ties -> lower col. 128 threads/row; per-thread sorted top-16 in registers
// (branchless shift-insert), wave0 merges the 128 lists -> top-48.
__global__ __launch_bounds__(128) void topk_cand(const unsigned short* __restrict__ scores,
                                                 int Hc, int c0,
                                                 unsigned* __restrict__ cand) {
  __shared__ unsigned lk[128 * 17];
  const int row = blockIdx.x;
  const int t = threadIdx.x;
  unsigned s[PT];
#pragma unroll
  for (int j = 0; j < PT; ++j) s[j] = 0u;

  const unsigned short* srow = scores + (size_t)row * Hc;
  for (int cb = t * 8; cb < Hc; cb += 128 * 8) {
    short8_t v = *(const short8_t*)(srow + cb);
    int gcb = c0 + cb;
#pragma unroll
    for (int e = 0; e < 8; ++e) {
      unsigned val = (unsigned)(unsigned short)v[e];
      unsigned key = (val << 16) | (unsigned)(0x7FFF - (gcb + e));
      if (key > s[PT - 1]) {
        unsigned prev = 0xFFFFFFFFu;
#pragma unroll
        for (int j = 0; j < PT; ++j) {
          unsigned sj = s[j];
          s[j] = (sj >= key) ? sj : (prev < key ? prev : key);
          prev = sj;
        }
      }
    }
  }
  // merge running candidates from previous chunks
  if (t < KC) {
    unsigned key = cand[row * KC + t];
    if (key > s[PT - 1]) {
      unsigned prev = 0xFFFFFFFFu;
#pragma unroll
      for (int j = 0; j < PT; ++j) {
        unsigned sj = s[j];
        s[j] = (sj >= key) ? sj : (prev < key ? prev : key);
        prev = sj;
      }
    }
  }
#pragma unroll
  for (int j = 0; j < PT; ++j) lk[t * 17 + j] = s[j];
  __syncthreads();

  if (t < 64) {
    unsigned k0 = lk[t * 17];
    unsigned k1 = lk[(t + 64) * 17];
    int h0 = 0, h1 = 0;
    unsigned mywin = 0;
    for (int it = 0; it < KC; ++it) {
      unsigned wmax = (k0 > k1) ? k0 : k1;
#pragma unroll
      for (int off = 32; off >= 1; off >>= 1) {
        unsigned o = __shfl_down(wmax, (unsigned)off);
        if (o > wmax) wmax = o;
      }
      wmax = __shfl(wmax, 0);
      if (it == t) mywin = wmax;
      if (k0 == wmax)      { ++h0; k0 = (h0 < PT) ? lk[t * 17 + h0] : 0u; }
      else if (k1 == wmax) { ++h1; k1 = (h1 < PT) ? lk[(t + 64) * 17 + h1] : 0u; }
    }
    if (t < KC) cand[row * KC + t] = mywin;
  }
}

// ---------------- fused exact rescore + top-32 select + decode ----------------
__global__ __launch_bounds__(256) void rescore_decode(
    const unsigned* __restrict__ cand,
    const float* __restrict__ x, const float* __restrict__ Wenc,
    const float* __restrict__ benc,
    const float* __restrict__ Wdec, const float* __restrict__ bdec,
    float* __restrict__ out) {
  __shared__ float xr[DIN];
  __shared__ double sc[KC];
  __shared__ int   scol[KC];
  __shared__ float fv[KTOP];
  __shared__ int   fi[KTOP];
  const int row = blockIdx.x, t = threadIdx.x;

  {
    float4 xv = *(const float4*)(x + (size_t)row * DIN + t * 4);
    float4 bv = *(const float4*)(bdec + t * 4);
    *(float4*)(xr + t * 4) = make_float4(xv.x - bv.x, xv.y - bv.y, xv.z - bv.z, xv.w - bv.w);
  }
  if (t < KC) scol[t] = 0x7FFF - (int)(cand[row * KC + t] & 0xFFFFu);
  if (t < KTOP) { fv[t] = 0.f; fi[t] = 0; }
  __syncthreads();

  const int wave = t >> 6, lane = t & 63;
  for (int j = wave; j < KC; j += 4) {
    int col = scol[j];
    const float* wr = Wenc + (size_t)col * DIN;
    double p = 0.0;
#pragma unroll
    for (int q = 0; q < 4; ++q) {
      int o = q * 256 + lane * 4;
      float4 w = *(const float4*)(wr + o);
      float4 xv = *(const float4*)(xr + o);
      p += (double)xv.x * (double)w.x + (double)xv.y * (double)w.y +
           (double)xv.z * (double)w.z + (double)xv.w * (double)w.w;
    }
#pragma unroll
    for (int off = 32; off >= 1; off >>= 1) p += __shfl_down(p, off);
    if (lane == 0) {
      double v = p + (double)benc[col];
      sc[j] = v > 0.0 ? v : 0.0;
    }
  }
  __syncthreads();

  // rank among 48 (numpy tie semantics: higher val first, then lower col)
  if (t < KC) {
    double mv = sc[t];
    int mc = scol[t];
    int rank = 0;
    for (int j = 0; j < KC; ++j) {
      double oj = sc[j];
      if (oj > mv || (oj == mv && (scol[j] < mc || (scol[j] == mc && j < t)))) ++rank;
    }
    if (rank < KTOP) { fv[rank] = (float)mv; fi[rank] = mc; }
  }
  __syncthreads();

  const int c = t * 4;
  float4 bd = *(const float4*)(bdec + c);
  float a0 = bd.x, a1 = bd.y, a2 = bd.z, a3 = bd.w;
#pragma unroll 8
  for (int j = 0; j < KTOP; ++j) {
    float v = fv[j];
    float4 w = *(const float4*)(Wdec + (size_t)fi[j] * DIN + c);
    a0 += v * w.x; a1 += v * w.y; a2 += v * w.z; a3 += v * w.w;
  }
  *(float4*)(out + (size_t)row * DIN + c) = make_float4(a0, a1, a2, a3);
}

extern "C" void kernel_launch(void* const* d_in, const int* in_sizes, int n_in,
                              void* d_out, int out_size, void* d_ws, size_t ws_size,
                              hipStream_t stream) {
  const float* x    = (const float*)d_in[0];
  const float* Wenc = (const float*)d_in[1];
  const float* benc = (const float*)d_in[2];
  const float* Wdec = (const float*)d_in[3];
  const float* bdec = (const float*)d_in[4];
  // d_in[5] is k (==32), baked into KTOP.
  float* out = (float*)d_out;

  char* ws = (char*)d_ws;
  unsigned short* xbf  = (unsigned short*)ws;                 // 8 MB
  unsigned*       cand = (unsigned*)(ws + (8u << 20));        // 768 KB

  // fit chunk size: 9MB + Hc*2048 (Wbc) + 4096*Hc*2 (scores) <= ws_size
  const size_t fixed = (size_t)(9u << 20);
  int Hc = HID;
  while (Hc > 128 &&
         fixed + (size_t)Hc * DIN * 2 + (size_t)BROWS * Hc * 2 > ws_size)
    Hc >>= 1;

  unsigned short* Wbc    = (unsigned short*)(ws + fixed);
  unsigned short* scores = (unsigned short*)(ws + fixed + (size_t)Hc * DIN * 2);

  prep_x<<<BROWS * DIN / 1024, 256, 0, stream>>>(x, bdec, xbf);
  init_cand<<<(BROWS * KC + 255) / 256, 256, 0, stream>>>(cand);
  for (int c0 = 0; c0 < HID; c0 += Hc) {
    conv_wc<<<Hc, 256, 0, stream>>>(Wenc, Wbc, c0);
    gemm_scores<<<dim3(Hc / BN, BROWS / BM), 256, 0, stream>>>(xbf, Wbc, benc, scores, Hc, c0);
    topk_cand<<<BROWS, 128, 0, stream>>>(scores, Hc, c0, cand);
  }
  rescore_decode<<<BROWS, 256, 0, stream>>>(cand, x, Wenc, benc, Wdec, bdec, out);
}